// Round 12
// baseline (77.620 us; speedup 1.0000x reference)
//
#include <hip/hip_runtime.h>
#include <hip/hip_fp16.h>
#include <math.h>

#define BB 8
#define HH 128
#define WW 128
#define CC 64
#define KK 9
#define OUTC 64
#define TW 16
#define KTOT 576          // kappa = k*64 + c
#define NELEM (BB*HH*WW*CC)
#define NPAIR (BB*HH*WW*KK)

typedef __attribute__((ext_vector_type(8))) _Float16 half8v;
typedef __attribute__((ext_vector_type(4))) float float4v;

static __device__ __forceinline__ unsigned short f2h(float f) {
    return __half_as_ushort(__float2half(f));   // RNE
}
static __device__ __forceinline__ __half2 bits2h(unsigned w) {
    __half2 h; __builtin_memcpy(&h, &w, 4); return h;
}

// Swizzled MFMA-fragment LDS offset (ushort units) for cols (pixel p, kappa).
static __device__ __forceinline__ int frag_addr(int p, int kappa) {
    int chunk = kappa >> 3;
    return ((chunk >> 2) << 9) + ((chunk & 3) << 7) + ((p ^ (chunk & 7)) << 3) + (kappa & 7);
}

// ---- prep: weights -> f16 FRAGMENT-ORDER panels; x -> f16 copy ----
__global__ __launch_bounds__(256) void prep_all(
    const float* __restrict__ x, const float* __restrict__ offk,
    const float* __restrict__ mk, const float* __restrict__ filt,
    unsigned short* __restrict__ fbf,  // [4*18*512]
    unsigned short* __restrict__ wcf,  // [2*18*512]
    unsigned short* __restrict__ xf,   // f16 copy of x
    int do_x)
{
    int bid = blockIdx.x, tid = threadIdx.x;
    if (bid < 144) {
        int j = bid * 256 + tid;                 // 36864 total
        {
            int w = j / 9216, rem = j - w * 9216;
            int ks = rem >> 9, ln = (rem >> 3) & 63, sj = rem & 7;
            int pl = ln & 15, lg = ln >> 4;
            int o = w * 16 + pl, kap = ks * 32 + lg * 8 + sj;
            int k = kap >> 6, c = kap & 63;
            fbf[j] = f2h(filt[(o * CC + c) * KK + k]);
        }
        if (j < 18432) {
            int nh = j / 9216, rem = j - nh * 9216;
            int ks = rem >> 9, ln = (rem >> 3) & 63, sj = rem & 7;
            int pl = ln & 15, lg = ln >> 4;
            int o = nh * 16 + pl, kap = ks * 32 + lg * 8 + sj;
            int k = kap >> 6, c = kap & 63;
            float v = 0.f;
            if (o < 18)      v = offk[(k * CC + c) * 18 + o];
            else if (o < 27) v = mk[(k * CC + c) * 9 + (o - 18)];
            wcf[j] = f2h(v);
        }
        return;
    }
    if (!do_x) return;
    int i = (bid - 144) * 256 + tid;          // 8 elems/thread, 4096 blocks exact
    const float* src = x + (size_t)i * 8;
    float4 a = *(const float4*)(src);
    float4 c = *(const float4*)(src + 4);
    float v[8] = {a.x, a.y, a.z, a.w, c.x, c.y, c.z, c.w};
    unsigned q[4];
#pragma unroll
    for (int j = 0; j < 4; ++j)
        q[j] = (unsigned)f2h(v[2 * j]) | ((unsigned)f2h(v[2 * j + 1]) << 16);
    *(uint4*)(xf + (size_t)i * 8) = make_uint4(q[0], q[1], q[2], q[3]);
}

// ---- Kernel A: offset/mask conv + gather-descriptor setup -> gsa/gsw -------
__global__ __launch_bounds__(256, 8) void conv_setup(
    const unsigned short* __restrict__ xf,
    const unsigned short* __restrict__ wcf,
    unsigned* __restrict__ gsa,        // per (pixel,tap): packed c00 + flags
    uint2* __restrict__ gsw)           // per (pixel,tap): 4 packed f16 weights
{
    __shared__ __align__(16) unsigned short tile[3 * 18 * 64];  // 6912 B
    __shared__ float ps2[4][TW][18];                             // 4608 B

    const int tid  = threadIdx.x;
    const int lane = tid & 63;
    const int wave = tid >> 6;
    const int pl = lane & 15;
    const int lg = lane >> 4;

    const int swz = (blockIdx.x & 7) * 1024 + (blockIdx.x >> 3);
    const int bw = swz & 7;
    const int h  = (swz >> 3) & 127;
    const int b  = swz >> 10;
    const int w0 = bw * TW;

    // stage x tile [3 rows][18 px][64 ch] f16, coalesced, XOR-swizzled
#pragma unroll
    for (int it = 0; it < 2; ++it) {
        int e = tid + it * 256;
        if (it == 1 && tid >= 176) break;
        int r    = (e >= 288) ? 2 : (e >= 144) ? 1 : 0;
        int rem2 = e - r * 144;
        int px   = rem2 >> 3;
        int c8   = rem2 & 7;
        int y = h + r - 1, xg = w0 + px - 1;
        int lidx = (r * 18 + px) * 64 + ((c8 * 8) ^ ((px & 7) << 3));
        uint4 val = make_uint4(0u, 0u, 0u, 0u);
        if ((unsigned)y < (unsigned)HH && (unsigned)xg < (unsigned)WW)
            val = *(const uint4*)(xf + ((b * HH + y) * WW + xg) * CC + c8 * 8);
        *(uint4*)(tile + lidx) = val;
    }
    __syncthreads();

    // conv via MFMA (f16): A from LDS tile, B contiguous fragment panel
    const int nh = wave & 1, kh = wave >> 1;
    float4v acc = {0.f, 0.f, 0.f, 0.f};
    __builtin_amdgcn_s_setprio(1);
#pragma unroll
    for (int ks9 = 0; ks9 < 9; ++ks9) {
        const int ksg = kh * 9 + ks9;
        const int tap = ksg >> 1;
        const int cb  = (ksg & 1) * 32 + lg * 8;
        const int ky = tap / 3, kx = tap - ky * 3;
        const int px = pl + kx;
        const int base = (ky * 18 + px) * 64 + (cb ^ ((px & 7) << 3));
        half8v af = *(const half8v*)(tile + base);
        half8v bv = *(const half8v*)(wcf + ((nh * 18 + ksg) << 9) + (lane << 3));
        acc = __builtin_amdgcn_mfma_f32_16x16x32_f16(af, bv, acc, 0, 0, 0);
    }
    __builtin_amdgcn_s_setprio(0);
#pragma unroll
    for (int r = 0; r < 4; ++r)
        ps2[wave][lg * 4 + r][pl] = acc[r];
    __syncthreads();

    // setup: reduce partials, compute corner descriptor, write to global
    if (tid < 144) {
        const int sp = tid / 9, sk = tid - (tid / 9) * 9;
        auto rd = [&](int o) {
            int nhh = o >> 4, col = o & 15;
            return ps2[nhh][sp][col] + ps2[2 + nhh][sp][col];
        };
        float s_dy = rd(2 * sk), s_dx = rd(2 * sk + 1), s_ml = rd(18 + sk);
        float m  = 1.f / (1.f + __expf(-s_ml));
        float py = (float)(h + (sk / 3) - 1) + s_dy;
        float px = (float)(w0 + sp + (sk % 3) - 1) + s_dx;
        float y0 = floorf(py), x0 = floorf(px);
        float ly = py - y0, lx = px - x0;
        bool vy0 = (y0 >= 0.f)  && (y0 <= 127.f);
        bool vy1 = (y0 >= -1.f) && (y0 <= 126.f);
        bool vx0 = (x0 >= 0.f)  && (x0 <= 127.f);
        bool vx1 = (x0 >= -1.f) && (x0 <= 126.f);
        float wy0 = 1.f - ly, wx0 = 1.f - lx;
        int iy0 = (int)fminf(fmaxf(y0, 0.f), 127.f);
        int ix0 = (int)fminf(fmaxf(x0, 0.f), 127.f);
        // clamp-aware deltas: +1 row/col only when it stays in-bounds
        bool fy = (y0 >= 0.f) && (y0 <= 126.f);
        bool fx = (x0 >= 0.f) && (x0 <= 126.f);
        int cc00 = b * (HH * WW * CC) + (iy0 * WW + ix0) * CC;   // < 2^24
        unsigned meta = (unsigned)cc00 | (fx ? (1u << 30) : 0u) | (fy ? (1u << 31) : 0u);
        float w0v = (vy0 && vx0) ? wy0 * wx0 * m : 0.f;
        float w1v = (vy0 && vx1) ? wy0 * lx  * m : 0.f;
        float w2v = (vy1 && vx0) ? ly  * wx0 * m : 0.f;
        float w3v = (vy1 && vx1) ? ly  * lx  * m : 0.f;
        unsigned w01 = (unsigned)f2h(w0v) | ((unsigned)f2h(w1v) << 16);
        unsigned w23 = (unsigned)f2h(w2v) | ((unsigned)f2h(w3v) << 16);
        int gp = ((b * HH + h) * WW + w0) * KK + tid;   // tid == sp*9+sk
        gsa[gp] = meta;
        gsw[gp] = make_uint2(w01, w23);
    }
}

// ---- Kernel B: gather (descriptor-driven) + einsum --------------------------
__global__ __launch_bounds__(256, 7) void gather_gemm(
    const unsigned short* __restrict__ xf,
    const unsigned* __restrict__ gsa,
    const uint2* __restrict__ gsw,
    const unsigned short* __restrict__ fbf,
    float* __restrict__ out)
{
    __shared__ __align__(16) unsigned short ims[TW * KTOT];   // 18432 B

    const int tid  = threadIdx.x;
    const int lane = tid & 63;
    const int wave = tid >> 6;
    const int pl = lane & 15;
    const int lg = lane >> 4;
    const int off_e = lg * 128 + ((pl ^ lg) << 3);
    const int off_o = lg * 128 + ((pl ^ (lg + 4)) << 3);

    const int swz = (blockIdx.x & 7) * 1024 + (blockIdx.x >> 3);
    const int bw = swz & 7;
    const int h  = (swz >> 3) & 127;
    const int b  = swz >> 10;
    const int w0 = bw * TW;

    // einsum B-fragment prefetch (independent of everything)
    const unsigned short* Bpf = fbf + ((wave * 18) << 9) + (lane << 3);
    half8v bp0 = *(const half8v*)(Bpf);
    half8v bp1 = *(const half8v*)(Bpf + 512);

    // preload ALL gather descriptors into named registers (no dependencies)
    const int gbase = ((b * HH + h) * WW + w0) * KK;
    const int c8 = tid & 7, co = c8 * 8;
    const int pr = tid >> 3;                       // 0..31
    const int pr4 = (pr + 128 < 144) ? pr + 128 : 143;
    uint  m0 = gsa[gbase + pr];       uint2 q0 = gsw[gbase + pr];
    uint  m1 = gsa[gbase + pr + 32];  uint2 q1 = gsw[gbase + pr + 32];
    uint  m2 = gsa[gbase + pr + 64];  uint2 q2 = gsw[gbase + pr + 64];
    uint  m3 = gsa[gbase + pr + 96];  uint2 q3 = gsw[gbase + pr + 96];
    uint  m4 = gsa[gbase + pr4];      uint2 q4 = gsw[gbase + pr4];

    auto gtask = [&](uint m, uint2 q, int pair) {
        int pp = (pair * 57) >> 9;         // pair/9 for pair<144
        int kk = pair - pp * 9;
        int c00 = (int)(m & 0x00FFFFFFu) + co;
        int dxo = (m & (1u << 30)) ? CC : 0;
        int dyo = (m & (1u << 31)) ? WW * CC : 0;
        int c01 = c00 + dxo;
        int c10 = c00 + dyo;
        int c11 = c01 + dyo;
        uint4 u00 = *(const uint4*)(xf + c00);
        uint4 u01 = *(const uint4*)(xf + c01);
        uint4 u10 = *(const uint4*)(xf + c10);
        uint4 u11 = *(const uint4*)(xf + c11);
        __half2 wv0 = __half2half2(__ushort_as_half((unsigned short)(q.x & 0xFFFF)));
        __half2 wv1 = __half2half2(__ushort_as_half((unsigned short)(q.x >> 16)));
        __half2 wv2 = __half2half2(__ushort_as_half((unsigned short)(q.y & 0xFFFF)));
        __half2 wv3 = __half2half2(__ushort_as_half((unsigned short)(q.y >> 16)));
        const unsigned* a00 = (const unsigned*)&u00;
        const unsigned* a01 = (const unsigned*)&u01;
        const unsigned* a10 = (const unsigned*)&u10;
        const unsigned* a11 = (const unsigned*)&u11;
        unsigned qq[4];
#pragma unroll
        for (int jj = 0; jj < 4; ++jj) {
            __half2 acc2 = __hmul2(bits2h(a00[jj]), wv0);
            acc2 = __hfma2(bits2h(a01[jj]), wv1, acc2);
            acc2 = __hfma2(bits2h(a10[jj]), wv2, acc2);
            acc2 = __hfma2(bits2h(a11[jj]), wv3, acc2);
            __builtin_memcpy(&qq[jj], &acc2, 4);
        }
        *(uint4*)(ims + frag_addr(pp, kk * 64 + co)) = make_uint4(qq[0], qq[1], qq[2], qq[3]);
    };

    gtask(m0, q0, pr);
    gtask(m1, q1, pr + 32);
    gtask(m2, q2, pr + 64);
    gtask(m3, q3, pr + 96);
    if (tid < 128) gtask(m4, q4, pr + 128);
    __syncthreads();

    // main einsum (f16): wave owns 16 outputs, even/odd accumulators
    {
        float4v accA = {0.f, 0.f, 0.f, 0.f}, accB = {0.f, 0.f, 0.f, 0.f};
        __builtin_amdgcn_s_setprio(1);
#pragma unroll
        for (int ks = 0; ks < 18; ++ks) {
            half8v a  = *(const half8v*)(ims + ks * 512 + ((ks & 1) ? off_o : off_e));
            half8v bv = (ks == 0) ? bp0 : (ks == 1) ? bp1
                      : *(const half8v*)(Bpf + (ks << 9));
            if (ks & 1) accB = __builtin_amdgcn_mfma_f32_16x16x32_f16(a, bv, accB, 0, 0, 0);
            else        accA = __builtin_amdgcn_mfma_f32_16x16x32_f16(a, bv, accA, 0, 0, 0);
        }
        __builtin_amdgcn_s_setprio(0);
        const int o = wave * 16 + pl;
        const size_t rowbase = (size_t)(b * HH + h) * WW + w0;
#pragma unroll
        for (int r = 0; r < 4; ++r) {
            int p = lg * 4 + r;
            out[(rowbase + p) * OUTC + o] = accA[r] + accB[r];
        }
    }
}

// ---- Fallback: R11 monolithic kernel (fp32 path, used only if ws too small) --
template<int HASB>
__global__ __launch_bounds__(256, 7) void deform_conv_fused(
    const float* __restrict__ x,
    const unsigned short* __restrict__ xf,
    const unsigned short* __restrict__ fbf,
    const unsigned short* __restrict__ wcf,
    float* __restrict__ out)
{
    __shared__ __align__(16) unsigned short ims[TW * KTOT];
    __shared__ __align__(16) union UU {
        float ps2[4][TW][18];
        struct { int4 c[144]; uint4 w[144]; } gs;
    } u;

    const int tid  = threadIdx.x;
    const int lane = tid & 63;
    const int wave = tid >> 6;
    const int pl = lane & 15;
    const int lg = lane >> 4;
    const int off_e = lg * 128 + ((pl ^ lg) << 3);
    const int off_o = lg * 128 + ((pl ^ (lg + 4)) << 3);

    const int swz = (blockIdx.x & 7) * 1024 + (blockIdx.x >> 3);
    const int bw = swz & 7;
    const int h  = (swz >> 3) & 127;
    const int b  = swz >> 10;
    const int w0 = bw * TW;

#pragma unroll
    for (int it = 0; it < 2; ++it) {
        int e = tid + it * 256;
        if (it == 1 && tid >= 176) break;
        int r    = (e >= 288) ? 2 : (e >= 144) ? 1 : 0;
        int rem2 = e - r * 144;
        int px   = rem2 >> 3;
        int c8   = rem2 & 7;
        int y = h + r - 1, xg = w0 + px - 1;
        int lidx = (r * 18 + px) * 64 + ((c8 * 8) ^ ((px & 7) << 3));
        uint4 val = make_uint4(0u, 0u, 0u, 0u);
        if ((unsigned)y < (unsigned)HH && (unsigned)xg < (unsigned)WW) {
            int goff = ((b * HH + y) * WW + xg) * CC + c8 * 8;
            if (HASB) {
                val = *(const uint4*)(xf + goff);
            } else {
                float4 v0 = *(const float4*)(x + goff);
                float4 v1 = *(const float4*)(x + goff + 4);
                float vv[8] = {v0.x, v0.y, v0.z, v0.w, v1.x, v1.y, v1.z, v1.w};
                unsigned q[4];
#pragma unroll
                for (int j = 0; j < 4; ++j)
                    q[j] = (unsigned)f2h(vv[2 * j]) | ((unsigned)f2h(vv[2 * j + 1]) << 16);
                val = make_uint4(q[0], q[1], q[2], q[3]);
            }
        }
        *(uint4*)(ims + lidx) = val;
    }
    __syncthreads();

    const int nh = wave & 1, kh = wave >> 1;
    float4v acc = {0.f, 0.f, 0.f, 0.f};
#pragma unroll
    for (int ks9 = 0; ks9 < 9; ++ks9) {
        const int ksg = kh * 9 + ks9;
        const int tap = ksg >> 1;
        const int cb  = (ksg & 1) * 32 + lg * 8;
        const int ky = tap / 3, kx = tap - ky * 3;
        const int px = pl + kx;
        const int base = (ky * 18 + px) * 64 + (cb ^ ((px & 7) << 3));
        half8v af = *(const half8v*)(ims + base);
        half8v bv = *(const half8v*)(wcf + ((nh * 18 + ksg) << 9) + (lane << 3));
        acc = __builtin_amdgcn_mfma_f32_16x16x32_f16(af, bv, acc, 0, 0, 0);
    }
#pragma unroll
    for (int r = 0; r < 4; ++r)
        u.ps2[wave][lg * 4 + r][pl] = acc[r];

    const unsigned short* Bpf = fbf + ((wave * 18) << 9) + (lane << 3);
    half8v bp0 = *(const half8v*)(Bpf);
    half8v bp1 = *(const half8v*)(Bpf + 512);
    __syncthreads();

    const int sp = tid / 9, sk = tid - (tid / 9) * 9;
    float s_dy = 0.f, s_dx = 0.f, s_ml = 0.f;
    if (tid < 144) {
        auto rd = [&](int o) {
            int nhh = o >> 4, col = o & 15;
            return u.ps2[nhh][sp][col] + u.ps2[2 + nhh][sp][col];
        };
        s_dy = rd(2 * sk); s_dx = rd(2 * sk + 1); s_ml = rd(18 + sk);
    }
    __syncthreads();

    if (tid < 144) {
        float m  = 1.f / (1.f + __expf(-s_ml));
        float py = (float)(h + (sk / 3) - 1) + s_dy;
        float px = (float)(w0 + sp + (sk % 3) - 1) + s_dx;
        float y0 = floorf(py), x0 = floorf(px);
        float ly = py - y0, lx = px - x0;
        bool vy0 = (y0 >= 0.f)  && (y0 <= 127.f);
        bool vy1 = (y0 >= -1.f) && (y0 <= 126.f);
        bool vx0 = (x0 >= 0.f)  && (x0 <= 127.f);
        bool vx1 = (x0 >= -1.f) && (x0 <= 126.f);
        float wy0 = 1.f - ly, wx0 = 1.f - lx;
        int iy0 = (int)fminf(fmaxf(y0, 0.f), 127.f);
        int iy1 = (int)fminf(fmaxf(y0 + 1.f, 0.f), 127.f);
        int ix0 = (int)fminf(fmaxf(x0, 0.f), 127.f);
        int ix1 = (int)fminf(fmaxf(x0 + 1.f, 0.f), 127.f);
        int base = b * (HH * WW * CC);
        u.gs.c[tid] = make_int4(base + (iy0 * WW + ix0) * CC,
                                base + (iy0 * WW + ix1) * CC,
                                base + (iy1 * WW + ix0) * CC,
                                base + (iy1 * WW + ix1) * CC);
        auto h2b = [](float f) { __half2 hh = __float2half2_rn(f);
                                 unsigned r; __builtin_memcpy(&r, &hh, 4); return r; };
        u.gs.w[tid] = make_uint4(h2b((vy0 && vx0) ? wy0 * wx0 * m : 0.f),
                                 h2b((vy0 && vx1) ? wy0 * lx  * m : 0.f),
                                 h2b((vy1 && vx0) ? ly  * wx0 * m : 0.f),
                                 h2b((vy1 && vx1) ? ly  * lx  * m : 0.f));
    }
    __syncthreads();

    for (int t = tid; t < 1152; t += 256) {
        int pair = t >> 3, c8 = t & 7;
        int p = pair / 9, k = pair - (pair / 9) * 9;
        int4  cc = u.gs.c[pair];
        uint4 wq = u.gs.w[pair];
        int co = c8 * 8;
        if (HASB) {
            __half2 wv0 = bits2h(wq.x), wv1 = bits2h(wq.y);
            __half2 wv2 = bits2h(wq.z), wv3 = bits2h(wq.w);
            uint4 u00 = *(const uint4*)(xf + cc.x + co);
            uint4 u01 = *(const uint4*)(xf + cc.y + co);
            uint4 u10 = *(const uint4*)(xf + cc.z + co);
            uint4 u11 = *(const uint4*)(xf + cc.w + co);
            const unsigned* a00 = (const unsigned*)&u00;
            const unsigned* a01 = (const unsigned*)&u01;
            const unsigned* a10 = (const unsigned*)&u10;
            const unsigned* a11 = (const unsigned*)&u11;
            unsigned qq[4];
#pragma unroll
            for (int jj = 0; jj < 4; ++jj) {
                __half2 acc2 = __hmul2(bits2h(a00[jj]), wv0);
                acc2 = __hfma2(bits2h(a01[jj]), wv1, acc2);
                acc2 = __hfma2(bits2h(a10[jj]), wv2, acc2);
                acc2 = __hfma2(bits2h(a11[jj]), wv3, acc2);
                __builtin_memcpy(&qq[jj], &acc2, 4);
            }
            *(uint4*)(ims + frag_addr(p, k * 64 + co)) = make_uint4(qq[0], qq[1], qq[2], qq[3]);
        } else {
            float wx = __half2float(bits2h(wq.x).x);
            float wy = __half2float(bits2h(wq.y).x);
            float wz = __half2float(bits2h(wq.z).x);
            float ww = __half2float(bits2h(wq.w).x);
            float r[8];
#pragma unroll
            for (int half = 0; half < 2; ++half) {
                float4 v00 = *(const float4*)(x + cc.x + co + half * 4);
                float4 v01 = *(const float4*)(x + cc.y + co + half * 4);
                float4 v10 = *(const float4*)(x + cc.z + co + half * 4);
                float4 v11 = *(const float4*)(x + cc.w + co + half * 4);
                r[half * 4 + 0] = wx * v00.x + wy * v01.x + wz * v10.x + ww * v11.x;
                r[half * 4 + 1] = wx * v00.y + wy * v01.y + wz * v10.y + ww * v11.y;
                r[half * 4 + 2] = wx * v00.z + wy * v01.z + wz * v10.z + ww * v11.z;
                r[half * 4 + 3] = wx * v00.w + wy * v01.w + wz * v10.w + ww * v11.w;
            }
            unsigned qq[4];
#pragma unroll
            for (int jj = 0; jj < 4; ++jj)
                qq[jj] = (unsigned)f2h(r[2 * jj]) | ((unsigned)f2h(r[2 * jj + 1]) << 16);
            *(uint4*)(ims + frag_addr(p, k * 64 + co)) = make_uint4(qq[0], qq[1], qq[2], qq[3]);
        }
    }
    __syncthreads();

    {
        float4v accA = {0.f, 0.f, 0.f, 0.f}, accB = {0.f, 0.f, 0.f, 0.f};
#pragma unroll
        for (int ks = 0; ks < 18; ++ks) {
            half8v a  = *(const half8v*)(ims + ks * 512 + ((ks & 1) ? off_o : off_e));
            half8v bv = (ks == 0) ? bp0 : (ks == 1) ? bp1
                      : *(const half8v*)(Bpf + (ks << 9));
            if (ks & 1) accB = __builtin_amdgcn_mfma_f32_16x16x32_f16(a, bv, accB, 0, 0, 0);
            else        accA = __builtin_amdgcn_mfma_f32_16x16x32_f16(a, bv, accA, 0, 0, 0);
        }
        const int o = wave * 16 + pl;
        const size_t rowbase = (size_t)(b * HH + h) * WW + w0;
#pragma unroll
        for (int r = 0; r < 4; ++r) {
            int p = lg * 4 + r;
            out[(rowbase + p) * OUTC + o] = accA[r] + accB[r];
        }
    }
}

extern "C" void kernel_launch(void* const* d_in, const int* in_sizes, int n_in,
                              void* d_out, int out_size, void* d_ws, size_t ws_size,
                              hipStream_t stream) {
    const float* x    = (const float*)d_in[0];
    const float* offk = (const float*)d_in[1];
    const float* mk   = (const float*)d_in[2];
    const float* filt = (const float*)d_in[3];
    float* out = (float*)d_out;
    // ws layout: fbf(73728) | wcf(36864) | xf(16.78MB) | gsa(4.72MB) | gsw(9.44MB)
    unsigned short* fbf = (unsigned short*)d_ws;
    unsigned short* wcf = fbf + OUTC * KTOT;
    unsigned short* xf  = wcf + 32 * KTOT;
    unsigned* gsa = (unsigned*)(xf + NELEM);
    uint2* gsw = (uint2*)(gsa + NPAIR);
    size_t need = (size_t)(OUTC + 32) * KTOT * 2 + (size_t)NELEM * 2
                + (size_t)NPAIR * 4 + (size_t)NPAIR * 8;      // 31,043,584 B
    int do_split = (ws_size >= need) ? 1 : 0;
    prep_all<<<144 + (do_split ? 4096 : 0), 256, 0, stream>>>(
        x, offk, mk, filt, fbf, wcf, xf, do_split);
    if (do_split) {
        conv_setup<<<BB * HH * (WW / TW), 256, 0, stream>>>(xf, wcf, gsa, gsw);
        gather_gemm<<<BB * HH * (WW / TW), 256, 0, stream>>>(xf, gsa, gsw, fbf, out);
    } else {
        deform_conv_fused<0><<<BB * HH * (WW / TW), 256, 0, stream>>>(
            x, nullptr, fbf, wcf, out);
    }
}

// Round 13
// 65.137 us; speedup vs baseline: 1.1916x; 1.1916x over previous
//
#include <hip/hip_runtime.h>
#include <hip/hip_fp16.h>
#include <math.h>

#define BB 8
#define HH 128
#define WW 128
#define CC 64
#define KK 9
#define OUTC 64
#define TW 16
#define KTOT 576          // kappa = k*64 + c
#define NELEM (BB*HH*WW*CC)

typedef __attribute__((ext_vector_type(8))) _Float16 half8v;
typedef __attribute__((ext_vector_type(4))) float float4v;

static __device__ __forceinline__ unsigned short f2h(float f) {
    return __half_as_ushort(__float2half(f));   // RNE
}
static __device__ __forceinline__ unsigned h2bits(float f) {
    __half2 h = __float2half2_rn(f);
    unsigned r; __builtin_memcpy(&r, &h, 4); return r;
}
static __device__ __forceinline__ __half2 bits2h(unsigned w) {
    __half2 h; __builtin_memcpy(&h, &w, 4); return h;
}

// Swizzled MFMA-fragment LDS offset (ushort units) for cols (pixel p, kappa).
static __device__ __forceinline__ int frag_addr(int p, int kappa) {
    int chunk = kappa >> 3;
    return ((chunk >> 2) << 9) + ((chunk & 3) << 7) + ((p ^ (chunk & 7)) << 3) + (kappa & 7);
}

// ---- prep: weights -> f16 FRAGMENT-ORDER panels; x -> f16 copy ----
__global__ __launch_bounds__(256) void prep_all(
    const float* __restrict__ x, const float* __restrict__ offk,
    const float* __restrict__ mk, const float* __restrict__ filt,
    unsigned short* __restrict__ fbf,  // [4*18*512]
    unsigned short* __restrict__ wcf,  // [2*18*512]
    unsigned short* __restrict__ xf,   // f16 copy of x
    int do_x)
{
    int bid = blockIdx.x, tid = threadIdx.x;
    if (bid < 144) {
        int j = bid * 256 + tid;                 // 36864 total
        {
            int w = j / 9216, rem = j - w * 9216;
            int ks = rem >> 9, ln = (rem >> 3) & 63, sj = rem & 7;
            int pl = ln & 15, lg = ln >> 4;
            int o = w * 16 + pl, kap = ks * 32 + lg * 8 + sj;
            int k = kap >> 6, c = kap & 63;
            fbf[j] = f2h(filt[(o * CC + c) * KK + k]);
        }
        if (j < 18432) {
            int nh = j / 9216, rem = j - nh * 9216;
            int ks = rem >> 9, ln = (rem >> 3) & 63, sj = rem & 7;
            int pl = ln & 15, lg = ln >> 4;
            int o = nh * 16 + pl, kap = ks * 32 + lg * 8 + sj;
            int k = kap >> 6, c = kap & 63;
            float v = 0.f;
            if (o < 18)      v = offk[(k * CC + c) * 18 + o];
            else if (o < 27) v = mk[(k * CC + c) * 9 + (o - 18)];
            wcf[j] = f2h(v);
        }
        return;
    }
    if (!do_x) return;
    int i = (bid - 144) * 256 + tid;          // 8 elems/thread, 4096 blocks exact
    const float* src = x + (size_t)i * 8;
    float4 a = *(const float4*)(src);
    float4 c = *(const float4*)(src + 4);
    float v[8] = {a.x, a.y, a.z, a.w, c.x, c.y, c.z, c.w};
    unsigned q[4];
#pragma unroll
    for (int j = 0; j < 4; ++j)
        q[j] = (unsigned)f2h(v[2 * j]) | ((unsigned)f2h(v[2 * j + 1]) << 16);
    *(uint4*)(xf + (size_t)i * 8) = make_uint4(q[0], q[1], q[2], q[3]);
}

template<int HASB>
__global__ __launch_bounds__(256, 7) void deform_conv_fused(
    const float* __restrict__ x,
    const unsigned short* __restrict__ xf,
    const unsigned short* __restrict__ fbf,
    const unsigned short* __restrict__ wcf,
    float* __restrict__ out)
{
    // ims (cols, 18432B) overlays the conv x-tile (6912B f16, single plane).
    __shared__ __align__(16) unsigned short ims[TW * KTOT];
    __shared__ __align__(16) union UU {
        float ps2[4][TW][18];                      // conv partials
        struct { int4 c[144]; uint4 w[144]; } gs;  // gather setup (packed half2 w)
    } u;

    const int tid  = threadIdx.x;
    const int lane = tid & 63;
    const int wave = tid >> 6;
    const int pl = lane & 15;
    const int lg = lane >> 4;
    const int off_e = lg * 128 + ((pl ^ lg) << 3);
    const int off_o = lg * 128 + ((pl ^ (lg + 4)) << 3);

    // XCD swizzle: 8192 blocks, each XCD owns one image b.
    const int swz = (blockIdx.x & 7) * 1024 + (blockIdx.x >> 3);
    const int bw = swz & 7;
    const int h  = (swz >> 3) & 127;
    const int b  = swz >> 10;
    const int w0 = bw * TW;

    // -------- stage x tile [3 rows][18 px][64 ch] f16, coalesced -----------------
    // LDS index swizzle: channel chunk XOR (px&7) -> conv ds_reads <=2-way.
#pragma unroll
    for (int it = 0; it < 2; ++it) {
        int e = tid + it * 256;
        if (it == 1 && tid >= 176) break;
        int r    = (e >= 288) ? 2 : (e >= 144) ? 1 : 0;
        int rem2 = e - r * 144;
        int px   = rem2 >> 3;
        int c8   = rem2 & 7;
        int y = h + r - 1, xg = w0 + px - 1;
        int lidx = (r * 18 + px) * 64 + ((c8 * 8) ^ ((px & 7) << 3));
        uint4 val = make_uint4(0u, 0u, 0u, 0u);
        if ((unsigned)y < (unsigned)HH && (unsigned)xg < (unsigned)WW) {
            int goff = ((b * HH + y) * WW + xg) * CC + c8 * 8;
            if (HASB) {
                val = *(const uint4*)(xf + goff);
            } else {
                float4 v0 = *(const float4*)(x + goff);
                float4 v1 = *(const float4*)(x + goff + 4);
                float vv[8] = {v0.x, v0.y, v0.z, v0.w, v1.x, v1.y, v1.z, v1.w};
                unsigned q[4];
#pragma unroll
                for (int j = 0; j < 4; ++j)
                    q[j] = (unsigned)f2h(vv[2 * j]) | ((unsigned)f2h(vv[2 * j + 1]) << 16);
                val = make_uint4(q[0], q[1], q[2], q[3]);
            }
        }
        *(uint4*)(ims + lidx) = val;
    }
    __syncthreads();

    // -------- conv via MFMA (f16): A from LDS tile, B contiguous panel -----------
    const int nh = wave & 1, kh = wave >> 1;
    float4v acc = {0.f, 0.f, 0.f, 0.f};
    __builtin_amdgcn_s_setprio(1);
#pragma unroll
    for (int ks9 = 0; ks9 < 9; ++ks9) {
        const int ksg = kh * 9 + ks9;
        const int tap = ksg >> 1;
        const int cb  = (ksg & 1) * 32 + lg * 8;
        const int ky = tap / 3, kx = tap - ky * 3;
        const int px = pl + kx;
        const int base = (ky * 18 + px) * 64 + (cb ^ ((px & 7) << 3));
        half8v af = *(const half8v*)(ims + base);
        half8v bv = *(const half8v*)(wcf + ((nh * 18 + ksg) << 9) + (lane << 3));
        acc = __builtin_amdgcn_mfma_f32_16x16x32_f16(af, bv, acc, 0, 0, 0);
    }
    __builtin_amdgcn_s_setprio(0);
#pragma unroll
    for (int r = 0; r < 4; ++r)
        u.ps2[wave][lg * 4 + r][pl] = acc[r];

    // prefetch first einsum B-fragments (contiguous panel, live across barriers)
    const unsigned short* Bpf = fbf + ((wave * 18) << 9) + (lane << 3);
    half8v bp0 = *(const half8v*)(Bpf);
    half8v bp1 = *(const half8v*)(Bpf + 512);
    __syncthreads();

    // -------- setup part 1: read conv partials ------------------------------------
    const int sp = tid / 9, sk = tid - (tid / 9) * 9;
    float s_dy = 0.f, s_dx = 0.f, s_ml = 0.f;
    if (tid < 144) {
        auto rd = [&](int o) {
            int nhh = o >> 4, col = o & 15;
            return u.ps2[nhh][sp][col] + u.ps2[2 + nhh][sp][col];
        };
        s_dy = rd(2 * sk); s_dx = rd(2 * sk + 1); s_ml = rd(18 + sk);
    }
    __syncthreads();   // ps2 reads done; gs overlay + ims overwrite now safe

    // -------- setup part 2: corner bases + folded packed-f16 weights -> gs --------
    if (tid < 144) {
        float m  = 1.f / (1.f + __expf(-s_ml));
        float py = (float)(h + (sk / 3) - 1) + s_dy;
        float px = (float)(w0 + sp + (sk % 3) - 1) + s_dx;
        float y0 = floorf(py), x0 = floorf(px);
        float ly = py - y0, lx = px - x0;
        bool vy0 = (y0 >= 0.f)  && (y0 <= 127.f);
        bool vy1 = (y0 >= -1.f) && (y0 <= 126.f);
        bool vx0 = (x0 >= 0.f)  && (x0 <= 127.f);
        bool vx1 = (x0 >= -1.f) && (x0 <= 126.f);
        float wy0 = 1.f - ly, wx0 = 1.f - lx;
        int iy0 = (int)fminf(fmaxf(y0, 0.f), 127.f);
        int iy1 = (int)fminf(fmaxf(y0 + 1.f, 0.f), 127.f);
        int ix0 = (int)fminf(fmaxf(x0, 0.f), 127.f);
        int ix1 = (int)fminf(fmaxf(x0 + 1.f, 0.f), 127.f);
        int base = b * (HH * WW * CC);
        u.gs.c[tid] = make_int4(base + (iy0 * WW + ix0) * CC,
                                base + (iy0 * WW + ix1) * CC,
                                base + (iy1 * WW + ix0) * CC,
                                base + (iy1 * WW + ix1) * CC);
        u.gs.w[tid] = make_uint4(h2bits((vy0 && vx0) ? wy0 * wx0 * m : 0.f),
                                 h2bits((vy0 && vx1) ? wy0 * lx  * m : 0.f),
                                 h2bits((vy1 && vx0) ? ly  * wx0 * m : 0.f),
                                 h2bits((vy1 && vx1) ? ly  * lx  * m : 0.f));
    }
    __syncthreads();

    // -------- gather: explicit 2-deep named-register pipeline (T14) ---------------
    // thread -> 5 tasks: pair = prg + {0,32,64,96,128(<144)}, channel slice cog.
    // Two register sets pa/pb: issue task i+1's 4 loads BEFORE task i's math so
    // 2 tasks' L2 round-trips overlap (WAR on names bounds it to 2-deep, ~64 VGPR).
    const int cog = (tid & 7) * 8;
    const int prg = tid >> 3;                 // 0..31

#define GLOAD(P, cc)                                                        \
    P##0 = *(const uint4*)(xf + (cc).x + cog);                              \
    P##1 = *(const uint4*)(xf + (cc).y + cog);                              \
    P##2 = *(const uint4*)(xf + (cc).z + cog);                              \
    P##3 = *(const uint4*)(xf + (cc).w + cog);

#define GMATH(P, WQ, PAIRIDX, PRED)                                         \
    {                                                                       \
        int pairi = (PAIRIDX);                                              \
        int ppi = pairi / 9, kki = pairi - (pairi / 9) * 9;                 \
        __half2 wv0 = bits2h((WQ).x), wv1 = bits2h((WQ).y);                 \
        __half2 wv2 = bits2h((WQ).z), wv3 = bits2h((WQ).w);                 \
        const unsigned* s0 = (const unsigned*)&P##0;                        \
        const unsigned* s1 = (const unsigned*)&P##1;                        \
        const unsigned* s2 = (const unsigned*)&P##2;                        \
        const unsigned* s3 = (const unsigned*)&P##3;                        \
        unsigned qq[4];                                                     \
        _Pragma("unroll")                                                   \
        for (int jj = 0; jj < 4; ++jj) {                                    \
            __half2 acc2 = __hmul2(bits2h(s0[jj]), wv0);                    \
            acc2 = __hfma2(bits2h(s1[jj]), wv1, acc2);                      \
            acc2 = __hfma2(bits2h(s2[jj]), wv2, acc2);                      \
            acc2 = __hfma2(bits2h(s3[jj]), wv3, acc2);                      \
            __builtin_memcpy(&qq[jj], &acc2, 4);                            \
        }                                                                   \
        if (PRED)                                                           \
            *(uint4*)(ims + frag_addr(ppi, kki * 64 + cog)) =               \
                make_uint4(qq[0], qq[1], qq[2], qq[3]);                     \
    }

    if (HASB) {
        uint4 pa0, pa1, pa2, pa3, pb0, pb1, pb2, pb3;
        int4  ccr;
        uint4 wqa, wqb;

        ccr = u.gs.c[prg];       wqa = u.gs.w[prg];
        GLOAD(pa, ccr)
        ccr = u.gs.c[prg + 32];  wqb = u.gs.w[prg + 32];
        GLOAD(pb, ccr)
        GMATH(pa, wqa, prg, true)
        ccr = u.gs.c[prg + 64];  wqa = u.gs.w[prg + 64];
        GLOAD(pa, ccr)
        GMATH(pb, wqb, prg + 32, true)
        ccr = u.gs.c[prg + 96];  wqb = u.gs.w[prg + 96];
        GLOAD(pb, ccr)
        GMATH(pa, wqa, prg + 64, true)
        {
            int p4 = (tid < 128) ? prg + 128 : prg;   // dummy (valid) for tail lanes
            ccr = u.gs.c[p4];    wqa = u.gs.w[p4];
        }
        GLOAD(pa, ccr)
        GMATH(pb, wqb, prg + 96, true)
        GMATH(pa, wqa, (tid < 128) ? prg + 128 : prg, tid < 128)
    } else {
        for (int t = tid; t < 1152; t += 256) {
            int pair = t >> 3, c8 = t & 7;
            int p = pair / 9, k = pair - (pair / 9) * 9;
            int4  cc = u.gs.c[pair];
            uint4 wq = u.gs.w[pair];
            float wx = __half2float(bits2h(wq.x).x);
            float wy = __half2float(bits2h(wq.y).x);
            float wz = __half2float(bits2h(wq.z).x);
            float ww = __half2float(bits2h(wq.w).x);
            int co = c8 * 8;
            float r[8];
#pragma unroll
            for (int half = 0; half < 2; ++half) {
                float4 v00 = *(const float4*)(x + cc.x + co + half * 4);
                float4 v01 = *(const float4*)(x + cc.y + co + half * 4);
                float4 v10 = *(const float4*)(x + cc.z + co + half * 4);
                float4 v11 = *(const float4*)(x + cc.w + co + half * 4);
                r[half * 4 + 0] = wx * v00.x + wy * v01.x + wz * v10.x + ww * v11.x;
                r[half * 4 + 1] = wx * v00.y + wy * v01.y + wz * v10.y + ww * v11.y;
                r[half * 4 + 2] = wx * v00.z + wy * v01.z + wz * v10.z + ww * v11.z;
                r[half * 4 + 3] = wx * v00.w + wy * v01.w + wz * v10.w + ww * v11.w;
            }
            unsigned qq[4];
#pragma unroll
            for (int jj = 0; jj < 4; ++jj)
                qq[jj] = (unsigned)f2h(r[2 * jj]) | ((unsigned)f2h(r[2 * jj + 1]) << 16);
            *(uint4*)(ims + frag_addr(p, k * 64 + co)) = make_uint4(qq[0], qq[1], qq[2], qq[3]);
        }
    }
#undef GLOAD
#undef GMATH
    __syncthreads();

    // -------- main einsum (f16): wave owns 16 outputs, even/odd accumulators ------
    {
        float4v accA = {0.f, 0.f, 0.f, 0.f}, accB = {0.f, 0.f, 0.f, 0.f};
        __builtin_amdgcn_s_setprio(1);
#pragma unroll
        for (int ks = 0; ks < 18; ++ks) {
            half8v a  = *(const half8v*)(ims + ks * 512 + ((ks & 1) ? off_o : off_e));
            half8v bv = (ks == 0) ? bp0 : (ks == 1) ? bp1
                      : *(const half8v*)(Bpf + (ks << 9));
            if (ks & 1) accB = __builtin_amdgcn_mfma_f32_16x16x32_f16(a, bv, accB, 0, 0, 0);
            else        accA = __builtin_amdgcn_mfma_f32_16x16x32_f16(a, bv, accA, 0, 0, 0);
        }
        __builtin_amdgcn_s_setprio(0);
        const int o = wave * 16 + pl;
        const size_t rowbase = (size_t)(b * HH + h) * WW + w0;
#pragma unroll
        for (int r = 0; r < 4; ++r) {
            int p = lg * 4 + r;
            out[(rowbase + p) * OUTC + o] = accA[r] + accB[r];
        }
    }
}

extern "C" void kernel_launch(void* const* d_in, const int* in_sizes, int n_in,
                              void* d_out, int out_size, void* d_ws, size_t ws_size,
                              hipStream_t stream) {
    const float* x    = (const float*)d_in[0];
    const float* offk = (const float*)d_in[1];
    const float* mk   = (const float*)d_in[2];
    const float* filt = (const float*)d_in[3];
    float* out = (float*)d_out;
    unsigned short* fbf = (unsigned short*)d_ws;                // 73728 B
    unsigned short* wcf = fbf + OUTC * KTOT;                    // 36864 B
    unsigned short* xf  = wcf + 32 * KTOT;                      // 16.78 MB
    size_t need = (size_t)(OUTC + 32) * KTOT * 2 + (size_t)NELEM * 2;
    int do_x = (ws_size >= need) ? 1 : 0;
    prep_all<<<144 + (do_x ? 4096 : 0), 256, 0, stream>>>(x, offk, mk, filt, fbf, wcf, xf, do_x);
    if (do_x)
        deform_conv_fused<1><<<BB * HH * (WW / TW), 256, 0, stream>>>(x, xf, fbf, wcf, out);
    else
        deform_conv_fused<0><<<BB * HH * (WW / TW), 256, 0, stream>>>(x, xf, fbf, wcf, out);
}

// Round 14
// 64.840 us; speedup vs baseline: 1.1971x; 1.0046x over previous
//
#include <hip/hip_runtime.h>
#include <hip/hip_fp16.h>
#include <math.h>

#define BB 8
#define HH 128
#define WW 128
#define CC 64
#define KK 9
#define OUTC 64
#define TW 16
#define KTOT 576          // kappa = k*64 + c
#define NELEM (BB*HH*WW*CC)

typedef __attribute__((ext_vector_type(8))) _Float16 half8v;
typedef __attribute__((ext_vector_type(4))) float float4v;

static __device__ __forceinline__ unsigned short f2h(float f) {
    return __half_as_ushort(__float2half(f));   // RNE
}
static __device__ __forceinline__ unsigned h2bits(float f) {
    __half2 h = __float2half2_rn(f);
    unsigned r; __builtin_memcpy(&r, &h, 4); return r;
}
static __device__ __forceinline__ __half2 bits2h(unsigned w) {
    __half2 h; __builtin_memcpy(&h, &w, 4); return h;
}

// Swizzled MFMA-fragment LDS offset (ushort units) for cols (pixel p, kappa).
static __device__ __forceinline__ int frag_addr(int p, int kappa) {
    int chunk = kappa >> 3;
    return ((chunk >> 2) << 9) + ((chunk & 3) << 7) + ((p ^ (chunk & 7)) << 3) + (kappa & 7);
}

// ---- prep: weights -> f16 FRAGMENT-ORDER panels; x -> f16 copy ----
__global__ __launch_bounds__(256) void prep_all(
    const float* __restrict__ x, const float* __restrict__ offk,
    const float* __restrict__ mk, const float* __restrict__ filt,
    unsigned short* __restrict__ fbf,  // [4*18*512]
    unsigned short* __restrict__ wcf,  // [2*18*512]
    unsigned short* __restrict__ xf,   // f16 copy of x
    int do_x)
{
    int bid = blockIdx.x, tid = threadIdx.x;
    if (bid < 144) {
        int j = bid * 256 + tid;                 // 36864 total
        {
            int w = j / 9216, rem = j - w * 9216;
            int ks = rem >> 9, ln = (rem >> 3) & 63, sj = rem & 7;
            int pl = ln & 15, lg = ln >> 4;
            int o = w * 16 + pl, kap = ks * 32 + lg * 8 + sj;
            int k = kap >> 6, c = kap & 63;
            fbf[j] = f2h(filt[(o * CC + c) * KK + k]);
        }
        if (j < 18432) {
            int nh = j / 9216, rem = j - nh * 9216;
            int ks = rem >> 9, ln = (rem >> 3) & 63, sj = rem & 7;
            int pl = ln & 15, lg = ln >> 4;
            int o = nh * 16 + pl, kap = ks * 32 + lg * 8 + sj;
            int k = kap >> 6, c = kap & 63;
            float v = 0.f;
            if (o < 18)      v = offk[(k * CC + c) * 18 + o];
            else if (o < 27) v = mk[(k * CC + c) * 9 + (o - 18)];
            wcf[j] = f2h(v);
        }
        return;
    }
    if (!do_x) return;
    int i = (bid - 144) * 256 + tid;          // 8 elems/thread, 4096 blocks exact
    const float* src = x + (size_t)i * 8;
    float4 a = *(const float4*)(src);
    float4 c = *(const float4*)(src + 4);
    float v[8] = {a.x, a.y, a.z, a.w, c.x, c.y, c.z, c.w};
    unsigned q[4];
#pragma unroll
    for (int j = 0; j < 4; ++j)
        q[j] = (unsigned)f2h(v[2 * j]) | ((unsigned)f2h(v[2 * j + 1]) << 16);
    *(uint4*)(xf + (size_t)i * 8) = make_uint4(q[0], q[1], q[2], q[3]);
}

template<int HASB>
__global__ __launch_bounds__(256, 7) void deform_conv_fused(
    const float* __restrict__ x,
    const unsigned short* __restrict__ xf,
    const unsigned short* __restrict__ fbf,
    const unsigned short* __restrict__ wcf,
    float* __restrict__ out)
{
    // ims (cols, 18432B) overlays the conv x-tile (6912B f16, single plane).
    __shared__ __align__(16) unsigned short ims[TW * KTOT];
    __shared__ __align__(16) union UU {
        float ps2[4][TW][18];                      // conv partials
        struct { int4 c[144]; uint4 w[144]; } gs;  // gather setup (packed half2 w)
    } u;

    const int tid  = threadIdx.x;
    const int lane = tid & 63;
    const int wave = tid >> 6;
    const int pl = lane & 15;
    const int lg = lane >> 4;
    const int off_e = lg * 128 + ((pl ^ lg) << 3);
    const int off_o = lg * 128 + ((pl ^ (lg + 4)) << 3);

    // XCD swizzle: 8192 blocks, each XCD owns one image b.
    const int swz = (blockIdx.x & 7) * 1024 + (blockIdx.x >> 3);
    const int bw = swz & 7;
    const int h  = (swz >> 3) & 127;
    const int b  = swz >> 10;
    const int w0 = bw * TW;

    // -------- stage x tile [3 rows][18 px][64 ch] f16, coalesced -----------------
    // LDS index swizzle: channel chunk XOR (px&7) -> conv ds_reads <=2-way.
#pragma unroll
    for (int it = 0; it < 2; ++it) {
        int e = tid + it * 256;
        if (it == 1 && tid >= 176) break;
        int r    = (e >= 288) ? 2 : (e >= 144) ? 1 : 0;
        int rem2 = e - r * 144;
        int px   = rem2 >> 3;
        int c8   = rem2 & 7;
        int y = h + r - 1, xg = w0 + px - 1;
        int lidx = (r * 18 + px) * 64 + ((c8 * 8) ^ ((px & 7) << 3));
        uint4 val = make_uint4(0u, 0u, 0u, 0u);
        if ((unsigned)y < (unsigned)HH && (unsigned)xg < (unsigned)WW) {
            int goff = ((b * HH + y) * WW + xg) * CC + c8 * 8;
            if (HASB) {
                val = *(const uint4*)(xf + goff);
            } else {
                float4 v0 = *(const float4*)(x + goff);
                float4 v1 = *(const float4*)(x + goff + 4);
                float vv[8] = {v0.x, v0.y, v0.z, v0.w, v1.x, v1.y, v1.z, v1.w};
                unsigned q[4];
#pragma unroll
                for (int j = 0; j < 4; ++j)
                    q[j] = (unsigned)f2h(vv[2 * j]) | ((unsigned)f2h(vv[2 * j + 1]) << 16);
                val = make_uint4(q[0], q[1], q[2], q[3]);
            }
        }
        *(uint4*)(ims + lidx) = val;
    }
    __syncthreads();

    // -------- conv via MFMA (f16): A from LDS tile, B contiguous panel -----------
    const int nh = wave & 1, kh = wave >> 1;
    float4v acc = {0.f, 0.f, 0.f, 0.f};
    __builtin_amdgcn_s_setprio(1);
#pragma unroll
    for (int ks9 = 0; ks9 < 9; ++ks9) {
        const int ksg = kh * 9 + ks9;
        const int tap = ksg >> 1;
        const int cb  = (ksg & 1) * 32 + lg * 8;
        const int ky = tap / 3, kx = tap - ky * 3;
        const int px = pl + kx;
        const int base = (ky * 18 + px) * 64 + (cb ^ ((px & 7) << 3));
        half8v af = *(const half8v*)(ims + base);
        half8v bv = *(const half8v*)(wcf + ((nh * 18 + ksg) << 9) + (lane << 3));
        acc = __builtin_amdgcn_mfma_f32_16x16x32_f16(af, bv, acc, 0, 0, 0);
    }
    __builtin_amdgcn_s_setprio(0);
#pragma unroll
    for (int r = 0; r < 4; ++r)
        u.ps2[wave][lg * 4 + r][pl] = acc[r];

    // prefetch first einsum B-fragments (contiguous panel, live across barriers)
    const unsigned short* Bpf = fbf + ((wave * 18) << 9) + (lane << 3);
    half8v bp0 = *(const half8v*)(Bpf);
    half8v bp1 = *(const half8v*)(Bpf + 512);
    __syncthreads();

    // -------- setup part 1: read conv partials ------------------------------------
    const int sp = tid / 9, sk = tid - (tid / 9) * 9;
    float s_dy = 0.f, s_dx = 0.f, s_ml = 0.f;
    if (tid < 144) {
        auto rd = [&](int o) {
            int nhh = o >> 4, col = o & 15;
            return u.ps2[nhh][sp][col] + u.ps2[2 + nhh][sp][col];
        };
        s_dy = rd(2 * sk); s_dx = rd(2 * sk + 1); s_ml = rd(18 + sk);
    }
    __syncthreads();   // ps2 reads done; gs overlay + ims overwrite now safe

    // -------- setup part 2: corner bases + folded packed-f16 weights -> gs --------
    if (tid < 144) {
        float m  = 1.f / (1.f + __expf(-s_ml));
        float py = (float)(h + (sk / 3) - 1) + s_dy;
        float px = (float)(w0 + sp + (sk % 3) - 1) + s_dx;
        float y0 = floorf(py), x0 = floorf(px);
        float ly = py - y0, lx = px - x0;
        bool vy0 = (y0 >= 0.f)  && (y0 <= 127.f);
        bool vy1 = (y0 >= -1.f) && (y0 <= 126.f);
        bool vx0 = (x0 >= 0.f)  && (x0 <= 127.f);
        bool vx1 = (x0 >= -1.f) && (x0 <= 126.f);
        float wy0 = 1.f - ly, wx0 = 1.f - lx;
        int iy0 = (int)fminf(fmaxf(y0, 0.f), 127.f);
        int iy1 = (int)fminf(fmaxf(y0 + 1.f, 0.f), 127.f);
        int ix0 = (int)fminf(fmaxf(x0, 0.f), 127.f);
        int ix1 = (int)fminf(fmaxf(x0 + 1.f, 0.f), 127.f);
        int base = b * (HH * WW * CC);
        u.gs.c[tid] = make_int4(base + (iy0 * WW + ix0) * CC,
                                base + (iy0 * WW + ix1) * CC,
                                base + (iy1 * WW + ix0) * CC,
                                base + (iy1 * WW + ix1) * CC);
        u.gs.w[tid] = make_uint4(h2bits((vy0 && vx0) ? wy0 * wx0 * m : 0.f),
                                 h2bits((vy0 && vx1) ? wy0 * lx  * m : 0.f),
                                 h2bits((vy1 && vx0) ? ly  * wx0 * m : 0.f),
                                 h2bits((vy1 && vx1) ? ly  * lx  * m : 0.f));
    }
    __syncthreads();

    // -------- gather: 576 WIDE tasks (pair, c16): 8x16B loads in flight per wait --
    // Widening the task (not cross-task pipelining, which the compiler defeats)
    // halves the serialized L2 round-trips: ~2.25/thread instead of ~4.5.
    if (HASB) {
        auto gtask16 = [&](int task) {
            int pair = task >> 2;
            int co   = (task & 3) * 16;
            int4  cc = u.gs.c[pair];
            uint4 wq = u.gs.w[pair];
            int pp = pair / 9, kk = pair - (pair / 9) * 9;
            // 8 independent 16B loads (2 per corner), clustered before one wait
            uint4 u00a = *(const uint4*)(xf + cc.x + co);
            uint4 u00b = *(const uint4*)(xf + cc.x + co + 8);
            uint4 u01a = *(const uint4*)(xf + cc.y + co);
            uint4 u01b = *(const uint4*)(xf + cc.y + co + 8);
            uint4 u10a = *(const uint4*)(xf + cc.z + co);
            uint4 u10b = *(const uint4*)(xf + cc.z + co + 8);
            uint4 u11a = *(const uint4*)(xf + cc.w + co);
            uint4 u11b = *(const uint4*)(xf + cc.w + co + 8);
            __half2 wv0 = bits2h(wq.x), wv1 = bits2h(wq.y);
            __half2 wv2 = bits2h(wq.z), wv3 = bits2h(wq.w);
            const unsigned* s00a = (const unsigned*)&u00a;
            const unsigned* s01a = (const unsigned*)&u01a;
            const unsigned* s10a = (const unsigned*)&u10a;
            const unsigned* s11a = (const unsigned*)&u11a;
            const unsigned* s00b = (const unsigned*)&u00b;
            const unsigned* s01b = (const unsigned*)&u01b;
            const unsigned* s10b = (const unsigned*)&u10b;
            const unsigned* s11b = (const unsigned*)&u11b;
            unsigned qa[4], qb[4];
#pragma unroll
            for (int jj = 0; jj < 4; ++jj) {
                __half2 aa = __hmul2(bits2h(s00a[jj]), wv0);
                aa = __hfma2(bits2h(s01a[jj]), wv1, aa);
                aa = __hfma2(bits2h(s10a[jj]), wv2, aa);
                aa = __hfma2(bits2h(s11a[jj]), wv3, aa);
                __builtin_memcpy(&qa[jj], &aa, 4);
                __half2 bb = __hmul2(bits2h(s00b[jj]), wv0);
                bb = __hfma2(bits2h(s01b[jj]), wv1, bb);
                bb = __hfma2(bits2h(s10b[jj]), wv2, bb);
                bb = __hfma2(bits2h(s11b[jj]), wv3, bb);
                __builtin_memcpy(&qb[jj], &bb, 4);
            }
            *(uint4*)(ims + frag_addr(pp, kk * 64 + co)) = make_uint4(qa[0], qa[1], qa[2], qa[3]);
            *(uint4*)(ims + frag_addr(pp, kk * 64 + co + 8)) = make_uint4(qb[0], qb[1], qb[2], qb[3]);
        };
        gtask16(tid);
        gtask16(tid + 256);
        if (tid < 64) gtask16(tid + 512);
    } else {
        for (int t = tid; t < 1152; t += 256) {
            int pair = t >> 3, c8 = t & 7;
            int p = pair / 9, k = pair - (pair / 9) * 9;
            int4  cc = u.gs.c[pair];
            uint4 wq = u.gs.w[pair];
            float wx = __half2float(bits2h(wq.x).x);
            float wy = __half2float(bits2h(wq.y).x);
            float wz = __half2float(bits2h(wq.z).x);
            float ww = __half2float(bits2h(wq.w).x);
            int co = c8 * 8;
            float r[8];
#pragma unroll
            for (int half = 0; half < 2; ++half) {
                float4 v00 = *(const float4*)(x + cc.x + co + half * 4);
                float4 v01 = *(const float4*)(x + cc.y + co + half * 4);
                float4 v10 = *(const float4*)(x + cc.z + co + half * 4);
                float4 v11 = *(const float4*)(x + cc.w + co + half * 4);
                r[half * 4 + 0] = wx * v00.x + wy * v01.x + wz * v10.x + ww * v11.x;
                r[half * 4 + 1] = wx * v00.y + wy * v01.y + wz * v10.y + ww * v11.y;
                r[half * 4 + 2] = wx * v00.z + wy * v01.z + wz * v10.z + ww * v11.z;
                r[half * 4 + 3] = wx * v00.w + wy * v01.w + wz * v10.w + ww * v11.w;
            }
            unsigned qq[4];
#pragma unroll
            for (int jj = 0; jj < 4; ++jj)
                qq[jj] = (unsigned)f2h(r[2 * jj]) | ((unsigned)f2h(r[2 * jj + 1]) << 16);
            *(uint4*)(ims + frag_addr(p, k * 64 + co)) = make_uint4(qq[0], qq[1], qq[2], qq[3]);
        }
    }
    __syncthreads();

    // -------- main einsum (f16): wave owns 16 outputs, even/odd accumulators ------
    {
        float4v accA = {0.f, 0.f, 0.f, 0.f}, accB = {0.f, 0.f, 0.f, 0.f};
        __builtin_amdgcn_s_setprio(1);
#pragma unroll
        for (int ks = 0; ks < 18; ++ks) {
            half8v a  = *(const half8v*)(ims + ks * 512 + ((ks & 1) ? off_o : off_e));
            half8v bv = (ks == 0) ? bp0 : (ks == 1) ? bp1
                      : *(const half8v*)(Bpf + (ks << 9));
            if (ks & 1) accB = __builtin_amdgcn_mfma_f32_16x16x32_f16(a, bv, accB, 0, 0, 0);
            else        accA = __builtin_amdgcn_mfma_f32_16x16x32_f16(a, bv, accA, 0, 0, 0);
        }
        __builtin_amdgcn_s_setprio(0);
        const int o = wave * 16 + pl;
        const size_t rowbase = (size_t)(b * HH + h) * WW + w0;
#pragma unroll
        for (int r = 0; r < 4; ++r) {
            int p = lg * 4 + r;
            out[(rowbase + p) * OUTC + o] = accA[r] + accB[r];
        }
    }
}

extern "C" void kernel_launch(void* const* d_in, const int* in_sizes, int n_in,
                              void* d_out, int out_size, void* d_ws, size_t ws_size,
                              hipStream_t stream) {
    const float* x    = (const float*)d_in[0];
    const float* offk = (const float*)d_in[1];
    const float* mk   = (const float*)d_in[2];
    const float* filt = (const float*)d_in[3];
    float* out = (float*)d_out;
    unsigned short* fbf = (unsigned short*)d_ws;                // 73728 B
    unsigned short* wcf = fbf + OUTC * KTOT;                    // 36864 B
    unsigned short* xf  = wcf + 32 * KTOT;                      // 16.78 MB
    size_t need = (size_t)(OUTC + 32) * KTOT * 2 + (size_t)NELEM * 2;
    int do_x = (ws_size >= need) ? 1 : 0;
    prep_all<<<144 + (do_x ? 4096 : 0), 256, 0, stream>>>(x, offk, mk, filt, fbf, wcf, xf, do_x);
    if (do_x)
        deform_conv_fused<1><<<BB * HH * (WW / TW), 256, 0, stream>>>(x, xf, fbf, wcf, out);
    else
        deform_conv_fused<0><<<BB * HH * (WW / TW), 256, 0, stream>>>(x, xf, fbf, wcf, out);
}